// Round 4
// baseline (231.248 us; speedup 1.0000x reference)
//
#include <hip/hip_runtime.h>
#include <cstddef>

#define NN 100000
#define DD 128
#define ND (NN * DD)
#define BN_EPS 1e-5f
#define LDA 136                // LDS A row stride in bf16 elems (272 B, 16B-aligned)
#define NREP 16                // stats-accumulator replicas
#define NBKT 98                // scatter buckets: 1024 nodes each
#define EPB 4096               // edges per bcnt/k_bin block

typedef __bf16 bf16_t;
typedef bf16_t bf16x8 __attribute__((ext_vector_type(8)));
typedef float f32x4 __attribute__((ext_vector_type(4)));
typedef unsigned int uint;
typedef unsigned short ushort;

// ws 4-byte-slot layout:
//   [0, ND/2)            hb   (bf16 h, [NN][128])  -- pairs alias here pre-gemm
//   [ND/2, ND)           xb   (bf16 x)
//   base3 = ND:
//   csr[16*128], cqr[16*128], bktot[128], bcur[128]  (memset zeroes all),
//   cnt[NN], ptr0[NN], dinv[NN], srow[E], wb[4096 uints]

__device__ __forceinline__ ushort f2b(float f) {
    uint u = __builtin_bit_cast(uint, f);
    u += 0x7FFFu + ((u >> 16) & 1u);          // RNE
    return (ushort)(u >> 16);
}
__device__ __forceinline__ float b2f(uint s) {
    return __builtin_bit_cast(float, s << 16);
}

// int64 edge_index => high word of every entry is 0 (ids < 100000).
__device__ __forceinline__ int detect_i64(const int* __restrict__ ei) {
    __shared__ int sflag;
    int t = threadIdx.x;
    if (t < 64) {
        int hi = ei[2 * t + 1];
        unsigned long long b = __ballot(hi == 0);
        if (t == 0) sflag = (b == ~0ull) ? 1 : 0;
    }
    __syncthreads();
    return sflag;
}

// dual-role: blocks [0, nbh) LDS-histogram cols into bucket totals;
// rest pack x and W to bf16.
__global__ __launch_bounds__(256) void k_prep(const int* __restrict__ ei,
                                              int* __restrict__ bktot, int E, int nbh,
                                              const float* __restrict__ x,
                                              uint* __restrict__ xb,
                                              const float* __restrict__ W,
                                              uint* __restrict__ wb) {
    if ((int)blockIdx.x < nbh) {
        int f = detect_i64(ei);
        __shared__ int hist[NBKT];
        int t = threadIdx.x;
        if (t < NBKT) hist[t] = 0;
        __syncthreads();
        int base = blockIdx.x * EPB;
        int count = min(EPB, E - base);
        for (int i = t; i < count; i += 256) {
            int e = base + i;
            int c = f ? ei[2 * (E + e)] : ei[E + e];
            atomicAdd(&hist[c >> 10], 1);
        }
        __syncthreads();
        if (t < NBKT && hist[t] > 0) atomicAdd(&bktot[t], hist[t]);
        return;
    }
    int i = (blockIdx.x - nbh) * 256 + threadIdx.x;
    const float* src;
    uint* dst;
    int j;
    if (i < ND / 8) { src = x; dst = xb; j = i; }
    else { j = i - ND / 8; if (j >= (DD * DD) / 8) return; src = W; dst = wb; }
    const float4* s4 = (const float4*)src;
    float4 a = s4[2 * j], b = s4[2 * j + 1];
    uint4 o;
    o.x = (uint)f2b(a.x) | ((uint)f2b(a.y) << 16);
    o.y = (uint)f2b(a.z) | ((uint)f2b(a.w) << 16);
    o.z = (uint)f2b(b.x) | ((uint)f2b(b.y) << 16);
    o.w = (uint)f2b(b.z) | ((uint)f2b(b.w) << 16);
    ((uint4*)dst)[j] = o;
}

// partition edges into NBKT destination buckets. Bucket bases computed by a
// redundant per-block LDS scan of bktot (98 ints, trivial); global bcur holds
// only the in-bucket running offset (zero-initialized by memset).
__global__ __launch_bounds__(256) void k_bin(const int* __restrict__ ei,
                                             const int* __restrict__ bktot,
                                             int* __restrict__ bcur,
                                             uint2* __restrict__ pairs, int E) {
    int f = detect_i64(ei);
    __shared__ int bb[NBKT], hist[NBKT], scur[NBKT];
    int t = threadIdx.x;
    if (t < NBKT) { bb[t] = bktot[t]; hist[t] = 0; }
    __syncthreads();
    if (t == 0) {
        int run = 0;
        for (int i = 0; i < NBKT; ++i) { int v = bb[i]; bb[i] = run; run += v; }
    }
    int base = blockIdx.x * EPB;
    int count = min(EPB, E - base);
    int rr[16], cc[16];
#pragma unroll
    for (int k = 0; k < 16; ++k) {
        int i = t + k * 256;
        if (i < count) {
            int e = base + i;
            int r, c;
            if (f) { r = ei[2 * e]; c = ei[2 * (E + e)]; }
            else   { r = ei[e];     c = ei[E + e]; }
            rr[k] = r; cc[k] = c;
            atomicAdd(&hist[c >> 10], 1);
        }
    }
    __syncthreads();   // joins t0's scan and the histogram
    if (t < NBKT) scur[t] = bb[t] + atomicAdd(&bcur[t], hist[t]);
    __syncthreads();
#pragma unroll
    for (int k = 0; k < 16; ++k) {
        int i = t + k * 256;
        if (i < count) {
            int b = cc[k] >> 10;
            int pos = atomicAdd(&scur[b], 1);
            pairs[pos] = (uint2){(uint)rr[k], (uint)cc[k]};
        }
    }
}

// one block per bucket: LDS histogram of the bucket's 1024 node counters,
// LDS scan -> ptr0/cnt/dinv (coalesced), then scatter srow with LDS atomics
// only. Bucket edge range recomputed from bktot locally.
__global__ __launch_bounds__(256) void k_cnt(const uint2* __restrict__ pairs,
                                             const int* __restrict__ bktot,
                                             int* __restrict__ ptr0,
                                             int* __restrict__ cnt,
                                             float* __restrict__ dinv,
                                             int* __restrict__ srow) {
    __shared__ int hist[1024];
    __shared__ int scur[1024];
    __shared__ int ls[256];
    __shared__ int bb[NBKT];
    __shared__ int se0, se1;
    int b = blockIdx.x;
    int t = threadIdx.x;
    if (t < NBKT) bb[t] = bktot[t];
#pragma unroll
    for (int i = 0; i < 4; ++i) hist[t + i * 256] = 0;
    __syncthreads();
    if (t == 0) {
        int run = 0;
        for (int i = 0; i < b; ++i) run += bb[i];
        se0 = run; se1 = run + bb[b];
    }
    __syncthreads();
    int e0 = se0, e1 = se1;
    int nodebase = b << 10;
    for (int i = e0 + t; i < e1; i += 256)
        atomicAdd(&hist[(int)pairs[i].y - nodebase], 1);
    __syncthreads();
    int c4[4];
    int lsum = 0;
#pragma unroll
    for (int i = 0; i < 4; ++i) { c4[i] = hist[t * 4 + i]; lsum += c4[i]; }
    ls[t] = lsum;
    __syncthreads();
    for (int o = 1; o < 256; o <<= 1) {
        int v = (t >= o) ? ls[t - o] : 0;
        __syncthreads();
        ls[t] += v;
        __syncthreads();
    }
    int run = ls[t] - lsum + e0;
#pragma unroll
    for (int i = 0; i < 4; ++i) {
        int idx = nodebase + t * 4 + i;
        if (idx < NN) {
            ptr0[idx] = run;
            cnt[idx] = c4[i];
            dinv[idx] = c4[i] > 0 ? rsqrtf((float)c4[i]) : 0.f;
        }
        scur[t * 4 + i] = run;
        run += c4[i];
    }
    __syncthreads();
    for (int i = e0 + t; i < e1; i += 256) {
        uint2 p = pairs[i];
        int pos = atomicAdd(&scur[(int)p.y - nodebase], 1);
        srow[pos] = (int)p.x;
    }
}

// FUSED gather + GEMM + stats. Block = 4 waves = 64 nodes.
// Gather: 2 nodes interleaved (A/B), 4-deep each -> 8 xb loads in flight;
// dinv[r] loaded as wave-uniform broadcast AFTER the rj shfl, so it issues
// in parallel with the xb row loads instead of serially before them.
__global__ __launch_bounds__(256, 4) void k_gg(const uint* __restrict__ xb,
                                               const int* __restrict__ srow,
                                               const int* __restrict__ ptr0,
                                               const int* __restrict__ cnt,
                                               const float* __restrict__ dinv,
                                               const ushort* __restrict__ wb,
                                               ushort* __restrict__ hb,
                                               float* __restrict__ csr,
                                               float* __restrict__ cqr) {
    __shared__ char smem[64 * LDA * 2];       // 17.4 KB; sA, later reused for cp/cq
    ushort* sAp = (ushort*)smem;
    int t = threadIdx.x;
    int wave = t >> 6, lane = t & 63;
    size_t rowbase = (size_t)blockIdx.x * 64;

    // --- gather phase: wave handles rows wave*16 .. wave*16+15, 2 at a time ---
    int mn = (int)rowbase + wave * 16 + (lane & 15);
    int sv = 0, kv = 0;
    float dv = 0.f;
    if (lane < 16 && mn < NN) { sv = ptr0[mn]; kv = cnt[mn]; dv = dinv[mn]; }

    for (int i = 0; i < 16; i += 2) {
        int sa0 = __shfl(sv, i),     kA = __shfl(kv, i);
        int sb0 = __shfl(sv, i + 1), kB = __shfl(kv, i + 1);
        float dA = __shfl(dv, i), dB = __shfl(dv, i + 1);
        float axA = 0.f, ayA = 0.f, axB = 0.f, ayB = 0.f;
        int kmax = max(kA, kB);
        for (int base = 0; base < kmax; base += 64) {
            int mA = kA - base; mA = mA > 64 ? 64 : mA;
            int mB = kB - base; mB = mB > 64 ? 64 : mB;
            int rjA = 0, rjB = 0;
            if (lane < mA) rjA = srow[sa0 + base + lane];
            if (lane < mB) rjB = srow[sb0 + base + lane];
            int mm = max(mA, mB);
            for (int j = 0; j < mm; j += 4) {
                int ra0 = __shfl(rjA, j),     rb0 = __shfl(rjB, j);
                int ra1 = __shfl(rjA, j + 1), rb1 = __shfl(rjB, j + 1);
                int ra2 = __shfl(rjA, j + 2), rb2 = __shfl(rjB, j + 2);
                int ra3 = __shfl(rjA, j + 3), rb3 = __shfl(rjB, j + 3);
                // 8 row loads + 8 broadcast weight loads, all independent
                uint va0 = xb[(size_t)ra0 * 64 + lane];
                uint vb0 = xb[(size_t)rb0 * 64 + lane];
                uint va1 = xb[(size_t)ra1 * 64 + lane];
                uint vb1 = xb[(size_t)rb1 * 64 + lane];
                uint va2 = xb[(size_t)ra2 * 64 + lane];
                uint vb2 = xb[(size_t)rb2 * 64 + lane];
                uint va3 = xb[(size_t)ra3 * 64 + lane];
                uint vb3 = xb[(size_t)rb3 * 64 + lane];
                float wa0 = dinv[ra0], wbb0 = dinv[rb0];
                float wa1 = dinv[ra1], wbb1 = dinv[rb1];
                float wa2 = dinv[ra2], wbb2 = dinv[rb2];
                float wa3 = dinv[ra3], wbb3 = dinv[rb3];
                // zero weights on tail steps (r defaults to row 0: safe load)
                wa0 = (j     < mA) ? wa0 : 0.f;  wbb0 = (j     < mB) ? wbb0 : 0.f;
                wa1 = (j + 1 < mA) ? wa1 : 0.f;  wbb1 = (j + 1 < mB) ? wbb1 : 0.f;
                wa2 = (j + 2 < mA) ? wa2 : 0.f;  wbb2 = (j + 2 < mB) ? wbb2 : 0.f;
                wa3 = (j + 3 < mA) ? wa3 : 0.f;  wbb3 = (j + 3 < mB) ? wbb3 : 0.f;
                axA = fmaf(wa0, b2f(va0 & 0xFFFFu), axA); ayA = fmaf(wa0, b2f(va0 >> 16), ayA);
                axA = fmaf(wa1, b2f(va1 & 0xFFFFu), axA); ayA = fmaf(wa1, b2f(va1 >> 16), ayA);
                axA = fmaf(wa2, b2f(va2 & 0xFFFFu), axA); ayA = fmaf(wa2, b2f(va2 >> 16), ayA);
                axA = fmaf(wa3, b2f(va3 & 0xFFFFu), axA); ayA = fmaf(wa3, b2f(va3 >> 16), ayA);
                axB = fmaf(wbb0, b2f(vb0 & 0xFFFFu), axB); ayB = fmaf(wbb0, b2f(vb0 >> 16), ayB);
                axB = fmaf(wbb1, b2f(vb1 & 0xFFFFu), axB); ayB = fmaf(wbb1, b2f(vb1 >> 16), ayB);
                axB = fmaf(wbb2, b2f(vb2 & 0xFFFFu), axB); ayB = fmaf(wbb2, b2f(vb2 >> 16), ayB);
                axB = fmaf(wbb3, b2f(vb3 & 0xFFFFu), axB); ayB = fmaf(wbb3, b2f(vb3 >> 16), ayB);
            }
        }
        *(uint*)(sAp + (wave * 16 + i) * LDA + lane * 2) =
            (uint)f2b(dA * axA) | ((uint)f2b(dA * ayA) << 16);
        *(uint*)(sAp + (wave * 16 + i + 1) * LDA + lane * 2) =
            (uint)f2b(dB * axB) | ((uint)f2b(dB * ayB) << 16);
    }
    __syncthreads();

    // --- GEMM phase ---
    int quad = lane >> 4, l16 = lane & 15;
    bf16x8 Af[4];
#pragma unroll
    for (int ks = 0; ks < 4; ++ks)
        Af[ks] = __builtin_bit_cast(
            bf16x8, *(const uint4*)(sAp + (wave * 16 + l16) * LDA + ks * 32 + quad * 8));
    __syncthreads();                           // sA dead; reuse its LDS for cp/cq
    float (*cp)[128] = (float (*)[128])smem;
    float (*cq)[128] = (float (*)[128])(smem + 4 * 128 * 4);

#pragma unroll
    for (int ct = 0; ct < 8; ++ct) {
        bf16x8 Bf[4];
#pragma unroll
        for (int ks = 0; ks < 4; ++ks)
            Bf[ks] = __builtin_bit_cast(
                bf16x8,
                *(const uint4*)(wb + (size_t)(ct * 16 + l16) * 128 + ks * 32 + quad * 8));
        f32x4 acc = (f32x4){0.f, 0.f, 0.f, 0.f};
#pragma unroll
        for (int ks = 0; ks < 4; ++ks)
            acc = __builtin_amdgcn_mfma_f32_16x16x32_bf16(Af[ks], Bf[ks], acc, 0, 0, 0);
        float ss = 0.f, qq = 0.f;
#pragma unroll
        for (int r = 0; r < 4; ++r) {
            float v = acc[r];
            ss += v; qq += v * v;
            size_t row = rowbase + wave * 16 + quad * 4 + r;
            if (row < NN) hb[row * 128 + ct * 16 + l16] = f2b(v);
        }
        ss += __shfl_xor(ss, 16); ss += __shfl_xor(ss, 32);
        qq += __shfl_xor(qq, 16); qq += __shfl_xor(qq, 32);
        if (quad == 0) { cp[wave][ct * 16 + l16] = ss; cq[wave][ct * 16 + l16] = qq; }
    }
    __syncthreads();
    if (t < 128) {
        int rep = (blockIdx.x & (NREP - 1)) * 128 + t;
        atomicAdd(&csr[rep], cp[0][t] + cp[1][t] + cp[2][t] + cp[3][t]);
        atomicAdd(&cqr[rep], cq[0][t] + cq[1][t] + cq[2][t] + cq[3][t]);
    }
}

// BN + relu + residual; folds the NREP stat replicas in LDS (no k_red).
// 16 elems/thread, 4096 elems (32 rows) per block.
__global__ __launch_bounds__(256) void k_final(const uint* __restrict__ hb,
                                               const uint* __restrict__ xb,
                                               const float* __restrict__ gamma,
                                               const float* __restrict__ beta,
                                               const float* __restrict__ csr,
                                               const float* __restrict__ cqr,
                                               float* __restrict__ out, int out_size) {
    __shared__ float sa[128], sb[128];
    int t = threadIdx.x;
    const float invN = 1.0f / NN;
    if (t < 128) {
        float s = 0.f;
        for (int i = 0; i < NREP; ++i) s += csr[i * 128 + t];
        sa[t] = s * invN;                       // mean (temp)
    } else {
        int c = t - 128;
        float s = 0.f;
        for (int i = 0; i < NREP; ++i) s += cqr[i * 128 + c];
        sb[c] = s * invN;                       // E[h^2] (temp)
    }
    __syncthreads();
    if (t < 128) {
        float m = sa[t];
        float var = sb[t] - m * m;
        float inv = rsqrtf(var + BN_EPS);
        float A = inv * gamma[t];
        float B = beta[t] - m * A;
        sa[t] = A; sb[t] = B;                   // res = max(h*A+B,0)+x
    }
    __syncthreads();

    int c0 = (t & 7) * 16;
    int u8 = blockIdx.x * 512 + t * 2;          // uint4 index (8 bf16 each)
    uint4 hv0 = ((const uint4*)hb)[u8], hv1 = ((const uint4*)hb)[u8 + 1];
    uint4 xv0 = ((const uint4*)xb)[u8], xv1 = ((const uint4*)xb)[u8 + 1];
    uint hu[8] = {hv0.x, hv0.y, hv0.z, hv0.w, hv1.x, hv1.y, hv1.z, hv1.w};
    uint xu[8] = {xv0.x, xv0.y, xv0.z, xv0.w, xv1.x, xv1.y, xv1.z, xv1.w};
    float res[16];
#pragma unroll
    for (int p = 0; p < 8; ++p) {
        int c = c0 + p * 2;
        float h0 = b2f(hu[p] & 0xFFFFu), h1 = b2f(hu[p] >> 16);
        float x0 = b2f(xu[p] & 0xFFFFu), x1 = b2f(xu[p] >> 16);
        res[2 * p]     = fmaxf(fmaf(h0, sa[c],     sb[c]),     0.f) + x0;
        res[2 * p + 1] = fmaxf(fmaf(h1, sa[c + 1], sb[c + 1]), 0.f) + x1;
    }
    float4* o4 = (float4*)out;
    int ob = blockIdx.x * 1024 + t * 4;
#pragma unroll
    for (int q = 0; q < 4; ++q)
        o4[ob + q] = (float4){res[4 * q], res[4 * q + 1], res[4 * q + 2], res[4 * q + 3]};
    if (blockIdx.x == 0 && t == 0 && out_size > ND) out[ND] = 0.0f;
}

extern "C" void kernel_launch(void* const* d_in, const int* in_sizes, int n_in,
                              void* d_out, int out_size, void* d_ws, size_t ws_size,
                              hipStream_t stream) {
    const float* x     = (const float*)d_in[0];
    const int*   ei    = (const int*)d_in[1];
    const float* W     = (const float*)d_in[2];
    const float* gamma = (const float*)d_in[4];
    const float* beta  = (const float*)d_in[5];
    float* ws = (float*)d_ws;
    float* out = (float*)d_out;

    uint*   hb       = (uint*)ws;
    uint*   xb       = hb + ND / 2;
    float*  csr      = (float*)(xb + ND / 2);          // 16*128
    float*  cqr      = csr + NREP * 128;               // 16*128
    int*    bktot    = (int*)(cqr + NREP * 128);       // 128 (zeroed)
    int*    bcur     = bktot + 128;                    // 128 (zeroed)
    int*    cnt      = bcur + 128;                     // NN
    int*    ptr0     = cnt + NN;                       // NN
    float*  dinv     = (float*)(ptr0 + NN);            // NN
    int*    srow     = (int*)(dinv + NN);              // E

    int E = in_sizes[1] / 2;
    uint* wb = (uint*)(srow + E);

    // pairs alias the hb region (dead until k_gg writes it):
    // pairs needs 2*E slots (1.6M); hb region = 6.4M slots.
    uint2* pairs = (uint2*)hb;

    int nbc = (ND / 8 + (DD * DD) / 8 + 255) / 256;
    int nbin = (E + EPB - 1) / EPB;

    // zero stat replicas + bucket totals + bucket cursors (contiguous)
    hipMemsetAsync(csr, 0, (size_t)(2 * NREP * 128 + 256) * 4, stream);
    k_prep<<<nbin + nbc, 256, 0, stream>>>(ei, bktot, E, nbin, x, xb, W, wb);
    k_bin<<<nbin, 256, 0, stream>>>(ei, bktot, bcur, pairs, E);
    k_cnt<<<NBKT, 256, 0, stream>>>(pairs, bktot, ptr0, cnt, dinv, srow);
    k_gg<<<(NN + 63) / 64, 256, 0, stream>>>(xb, srow, ptr0, cnt, dinv,
                                             (const ushort*)wb, (ushort*)hb, csr, cqr);
    k_final<<<ND / 4096, 256, 0, stream>>>(hb, xb, gamma, beta, csr, cqr,
                                           out, out_size);
}

// Round 5
// 227.686 us; speedup vs baseline: 1.0156x; 1.0156x over previous
//
#include <hip/hip_runtime.h>
#include <cstddef>

#define NN 100000
#define DD 128
#define ND (NN * DD)
#define BN_EPS 1e-5f
#define LDA 136                // LDS A row stride in bf16 elems (272 B, 16B-aligned)
#define NREP 16                // stats-accumulator replicas
#define NBKT 98                // scatter buckets: 1024 nodes each
#define EPB 4096               // edges per bcnt/k_bin block

typedef __bf16 bf16_t;
typedef bf16_t bf16x8 __attribute__((ext_vector_type(8)));
typedef float f32x4 __attribute__((ext_vector_type(4)));
typedef unsigned int uint;
typedef unsigned short ushort;

// ws 4-byte-slot layout:
//   [0, ND/2)            hb   (bf16 h, [NN][128])  -- pairs alias here pre-gemm
//   [ND/2, ND)           xb   (bf16 x)
//   base3 = ND:
//   csr[16*128], cqr[16*128], bktot[128], bcur[128]  (memset zeroes all),
//   cnt[NN], ptr0[NN], dinv[NN], srow[E], wb[4096 uints]

__device__ __forceinline__ ushort f2b(float f) {
    uint u = __builtin_bit_cast(uint, f);
    u += 0x7FFFu + ((u >> 16) & 1u);          // RNE
    return (ushort)(u >> 16);
}
__device__ __forceinline__ float b2f(uint s) {
    return __builtin_bit_cast(float, s << 16);
}

// int64 edge_index => high word of every entry is 0 (ids < 100000).
__device__ __forceinline__ int detect_i64(const int* __restrict__ ei) {
    __shared__ int sflag;
    int t = threadIdx.x;
    if (t < 64) {
        int hi = ei[2 * t + 1];
        unsigned long long b = __ballot(hi == 0);
        if (t == 0) sflag = (b == ~0ull) ? 1 : 0;
    }
    __syncthreads();
    return sflag;
}

// dual-role: blocks [0, nbh) LDS-histogram cols into bucket totals;
// rest pack x and W to bf16.
__global__ __launch_bounds__(256) void k_prep(const int* __restrict__ ei,
                                              int* __restrict__ bktot, int E, int nbh,
                                              const float* __restrict__ x,
                                              uint* __restrict__ xb,
                                              const float* __restrict__ W,
                                              uint* __restrict__ wb) {
    if ((int)blockIdx.x < nbh) {
        int f = detect_i64(ei);
        __shared__ int hist[NBKT];
        int t = threadIdx.x;
        if (t < NBKT) hist[t] = 0;
        __syncthreads();
        int base = blockIdx.x * EPB;
        int count = min(EPB, E - base);
        for (int i = t; i < count; i += 256) {
            int e = base + i;
            int c = f ? ei[2 * (E + e)] : ei[E + e];
            atomicAdd(&hist[c >> 10], 1);
        }
        __syncthreads();
        if (t < NBKT && hist[t] > 0) atomicAdd(&bktot[t], hist[t]);
        return;
    }
    int i = (blockIdx.x - nbh) * 256 + threadIdx.x;
    const float* src;
    uint* dst;
    int j;
    if (i < ND / 8) { src = x; dst = xb; j = i; }
    else { j = i - ND / 8; if (j >= (DD * DD) / 8) return; src = W; dst = wb; }
    const float4* s4 = (const float4*)src;
    float4 a = s4[2 * j], b = s4[2 * j + 1];
    uint4 o;
    o.x = (uint)f2b(a.x) | ((uint)f2b(a.y) << 16);
    o.y = (uint)f2b(a.z) | ((uint)f2b(a.w) << 16);
    o.z = (uint)f2b(b.x) | ((uint)f2b(b.y) << 16);
    o.w = (uint)f2b(b.z) | ((uint)f2b(b.w) << 16);
    ((uint4*)dst)[j] = o;
}

// partition edges into NBKT destination buckets. Bucket bases computed by a
// redundant per-block LDS scan of bktot (98 ints, trivial); global bcur holds
// only the in-bucket running offset (zero-initialized by memset).
__global__ __launch_bounds__(256) void k_bin(const int* __restrict__ ei,
                                             const int* __restrict__ bktot,
                                             int* __restrict__ bcur,
                                             uint2* __restrict__ pairs, int E) {
    int f = detect_i64(ei);
    __shared__ int bb[NBKT], hist[NBKT], scur[NBKT];
    int t = threadIdx.x;
    if (t < NBKT) { bb[t] = bktot[t]; hist[t] = 0; }
    __syncthreads();
    if (t == 0) {
        int run = 0;
        for (int i = 0; i < NBKT; ++i) { int v = bb[i]; bb[i] = run; run += v; }
    }
    int base = blockIdx.x * EPB;
    int count = min(EPB, E - base);
    int rr[16], cc[16];
#pragma unroll
    for (int k = 0; k < 16; ++k) {
        int i = t + k * 256;
        if (i < count) {
            int e = base + i;
            int r, c;
            if (f) { r = ei[2 * e]; c = ei[2 * (E + e)]; }
            else   { r = ei[e];     c = ei[E + e]; }
            rr[k] = r; cc[k] = c;
            atomicAdd(&hist[c >> 10], 1);
        }
    }
    __syncthreads();   // joins t0's scan and the histogram
    if (t < NBKT) scur[t] = bb[t] + atomicAdd(&bcur[t], hist[t]);
    __syncthreads();
#pragma unroll
    for (int k = 0; k < 16; ++k) {
        int i = t + k * 256;
        if (i < count) {
            int b = cc[k] >> 10;
            int pos = atomicAdd(&scur[b], 1);
            pairs[pos] = (uint2){(uint)rr[k], (uint)cc[k]};
        }
    }
}

// one block per bucket: LDS histogram of the bucket's 1024 node counters,
// LDS scan -> ptr0/cnt/dinv (coalesced), then scatter srow with LDS atomics
// only. Bucket edge range recomputed from bktot locally.
__global__ __launch_bounds__(256) void k_cnt(const uint2* __restrict__ pairs,
                                             const int* __restrict__ bktot,
                                             int* __restrict__ ptr0,
                                             int* __restrict__ cnt,
                                             float* __restrict__ dinv,
                                             int* __restrict__ srow) {
    __shared__ int hist[1024];
    __shared__ int scur[1024];
    __shared__ int ls[256];
    __shared__ int bb[NBKT];
    __shared__ int se0, se1;
    int b = blockIdx.x;
    int t = threadIdx.x;
    if (t < NBKT) bb[t] = bktot[t];
#pragma unroll
    for (int i = 0; i < 4; ++i) hist[t + i * 256] = 0;
    __syncthreads();
    if (t == 0) {
        int run = 0;
        for (int i = 0; i < b; ++i) run += bb[i];
        se0 = run; se1 = run + bb[b];
    }
    __syncthreads();
    int e0 = se0, e1 = se1;
    int nodebase = b << 10;
    for (int i = e0 + t; i < e1; i += 256)
        atomicAdd(&hist[(int)pairs[i].y - nodebase], 1);
    __syncthreads();
    int c4[4];
    int lsum = 0;
#pragma unroll
    for (int i = 0; i < 4; ++i) { c4[i] = hist[t * 4 + i]; lsum += c4[i]; }
    ls[t] = lsum;
    __syncthreads();
    for (int o = 1; o < 256; o <<= 1) {
        int v = (t >= o) ? ls[t - o] : 0;
        __syncthreads();
        ls[t] += v;
        __syncthreads();
    }
    int run = ls[t] - lsum + e0;
#pragma unroll
    for (int i = 0; i < 4; ++i) {
        int idx = nodebase + t * 4 + i;
        if (idx < NN) {
            ptr0[idx] = run;
            cnt[idx] = c4[i];
            dinv[idx] = c4[i] > 0 ? rsqrtf((float)c4[i]) : 0.f;
        }
        scur[t * 4 + i] = run;
        run += c4[i];
    }
    __syncthreads();
    for (int i = e0 + t; i < e1; i += 256) {
        uint2 p = pairs[i];
        int pos = atomicAdd(&scur[(int)p.y - nodebase], 1);
        srow[pos] = (int)p.x;
    }
}

// FUSED gather + GEMM + stats. Block = 8 waves = 512 threads, 64-node tile.
// Gather: each wave owns 8 nodes (2 interleaved at a time, 4-deep MLP each).
// GEMM: wave w computes row-group (w&3) x ct-half (w>>2): 16 MFMAs/wave.
// 8 waves/block -> 32 resident waves/CU (vs 15 before): latency hiding x2.
__global__ __launch_bounds__(512, 8) void k_gg(const uint* __restrict__ xb,
                                               const int* __restrict__ srow,
                                               const int* __restrict__ ptr0,
                                               const int* __restrict__ cnt,
                                               const float* __restrict__ dinv,
                                               const ushort* __restrict__ wb,
                                               ushort* __restrict__ hb,
                                               float* __restrict__ csr,
                                               float* __restrict__ cqr) {
    __shared__ char smem[64 * LDA * 2];       // 17.4 KB; sA, later reused for cp/cq
    ushort* sAp = (ushort*)smem;
    int t = threadIdx.x;
    int wave = t >> 6, lane = t & 63;
    uint rowbase = (uint)blockIdx.x * 64;

    // --- gather: wave handles rows wave*8 .. wave*8+7, 2 at a time ---
    int mn = (int)rowbase + wave * 8 + (lane & 7);
    int sv = 0, kv = 0;
    float dv = 0.f;
    if (lane < 8 && mn < NN) { sv = ptr0[mn]; kv = cnt[mn]; dv = dinv[mn]; }

    for (int i = 0; i < 8; i += 2) {
        int sa0 = __shfl(sv, i),     kA = __shfl(kv, i);
        int sb0 = __shfl(sv, i + 1), kB = __shfl(kv, i + 1);
        float dA = __shfl(dv, i), dB = __shfl(dv, i + 1);
        float axA = 0.f, ayA = 0.f, axB = 0.f, ayB = 0.f;
        int kmax = max(kA, kB);
        for (int base = 0; base < kmax; base += 64) {
            int mA = kA - base; mA = mA > 64 ? 64 : mA;
            int mB = kB - base; mB = mB > 64 ? 64 : mB;
            int rjA = 0, rjB = 0;
            if (lane < mA) rjA = srow[sa0 + base + lane];
            if (lane < mB) rjB = srow[sb0 + base + lane];
            int mm = max(mA, mB);
            for (int j = 0; j < mm; j += 4) {
                int ra0 = __shfl(rjA, j),     rb0 = __shfl(rjB, j);
                int ra1 = __shfl(rjA, j + 1), rb1 = __shfl(rjB, j + 1);
                int ra2 = __shfl(rjA, j + 2), rb2 = __shfl(rjB, j + 2);
                int ra3 = __shfl(rjA, j + 3), rb3 = __shfl(rjB, j + 3);
                // 8 row loads + 8 broadcast weight loads, all independent;
                // 32-bit indices -> SGPR-base + voffset addressing
                uint va0 = xb[((uint)ra0 << 6) + (uint)lane];
                uint vb0 = xb[((uint)rb0 << 6) + (uint)lane];
                uint va1 = xb[((uint)ra1 << 6) + (uint)lane];
                uint vb1 = xb[((uint)rb1 << 6) + (uint)lane];
                uint va2 = xb[((uint)ra2 << 6) + (uint)lane];
                uint vb2 = xb[((uint)rb2 << 6) + (uint)lane];
                uint va3 = xb[((uint)ra3 << 6) + (uint)lane];
                uint vb3 = xb[((uint)rb3 << 6) + (uint)lane];
                float wa0 = dinv[ra0], wbb0 = dinv[rb0];
                float wa1 = dinv[ra1], wbb1 = dinv[rb1];
                float wa2 = dinv[ra2], wbb2 = dinv[rb2];
                float wa3 = dinv[ra3], wbb3 = dinv[rb3];
                // zero weights on tail steps (r defaults to row 0: safe load)
                wa0 = (j     < mA) ? wa0 : 0.f;  wbb0 = (j     < mB) ? wbb0 : 0.f;
                wa1 = (j + 1 < mA) ? wa1 : 0.f;  wbb1 = (j + 1 < mB) ? wbb1 : 0.f;
                wa2 = (j + 2 < mA) ? wa2 : 0.f;  wbb2 = (j + 2 < mB) ? wbb2 : 0.f;
                wa3 = (j + 3 < mA) ? wa3 : 0.f;  wbb3 = (j + 3 < mB) ? wbb3 : 0.f;
                axA = fmaf(wa0, b2f(va0 & 0xFFFFu), axA); ayA = fmaf(wa0, b2f(va0 >> 16), ayA);
                axA = fmaf(wa1, b2f(va1 & 0xFFFFu), axA); ayA = fmaf(wa1, b2f(va1 >> 16), ayA);
                axA = fmaf(wa2, b2f(va2 & 0xFFFFu), axA); ayA = fmaf(wa2, b2f(va2 >> 16), ayA);
                axA = fmaf(wa3, b2f(va3 & 0xFFFFu), axA); ayA = fmaf(wa3, b2f(va3 >> 16), ayA);
                axB = fmaf(wbb0, b2f(vb0 & 0xFFFFu), axB); ayB = fmaf(wbb0, b2f(vb0 >> 16), ayB);
                axB = fmaf(wbb1, b2f(vb1 & 0xFFFFu), axB); ayB = fmaf(wbb1, b2f(vb1 >> 16), ayB);
                axB = fmaf(wbb2, b2f(vb2 & 0xFFFFu), axB); ayB = fmaf(wbb2, b2f(vb2 >> 16), ayB);
                axB = fmaf(wbb3, b2f(vb3 & 0xFFFFu), axB); ayB = fmaf(wbb3, b2f(vb3 >> 16), ayB);
            }
        }
        *(uint*)(sAp + (wave * 8 + i) * LDA + lane * 2) =
            (uint)f2b(dA * axA) | ((uint)f2b(dA * ayA) << 16);
        *(uint*)(sAp + (wave * 8 + i + 1) * LDA + lane * 2) =
            (uint)f2b(dB * axB) | ((uint)f2b(dB * ayB) << 16);
    }
    __syncthreads();

    // --- GEMM phase: wave = row-group (wave&3) x ct-half (wave>>2) ---
    int rg = wave & 3, chh = wave >> 2;
    int quad = lane >> 4, l16 = lane & 15;
    bf16x8 Af[4];
#pragma unroll
    for (int ks = 0; ks < 4; ++ks)
        Af[ks] = __builtin_bit_cast(
            bf16x8, *(const uint4*)(sAp + (rg * 16 + l16) * LDA + ks * 32 + quad * 8));
    __syncthreads();                           // sA dead; reuse its LDS for cp/cq
    float (*cp)[64] = (float (*)[64])smem;
    float (*cq)[64] = (float (*)[64])(smem + 8 * 64 * 4);

#pragma unroll
    for (int c = 0; c < 4; ++c) {
        int ctg = chh * 4 + c;
        bf16x8 Bf[4];
#pragma unroll
        for (int ks = 0; ks < 4; ++ks)
            Bf[ks] = __builtin_bit_cast(
                bf16x8,
                *(const uint4*)(wb + (uint)(ctg * 16 + l16) * 128 + ks * 32 + quad * 8));
        f32x4 acc = (f32x4){0.f, 0.f, 0.f, 0.f};
#pragma unroll
        for (int ks = 0; ks < 4; ++ks)
            acc = __builtin_amdgcn_mfma_f32_16x16x32_bf16(Af[ks], Bf[ks], acc, 0, 0, 0);
        float ss = 0.f, qq = 0.f;
#pragma unroll
        for (int r = 0; r < 4; ++r) {
            float v = acc[r];
            ss += v; qq += v * v;
            uint row = rowbase + rg * 16 + quad * 4 + r;
            if (row < NN) hb[row * 128u + (uint)(ctg * 16 + l16)] = f2b(v);
        }
        ss += __shfl_xor(ss, 16); ss += __shfl_xor(ss, 32);
        qq += __shfl_xor(qq, 16); qq += __shfl_xor(qq, 32);
        if (quad == 0) { cp[wave][c * 16 + l16] = ss; cq[wave][c * 16 + l16] = qq; }
    }
    __syncthreads();
    if (t < 128) {
        // column t: ct-half = t>>6 -> contributed by waves (t>>6)*4 .. +3
        int w0 = (t >> 6) * 4, lc = t & 63;
        float s = cp[w0][lc] + cp[w0 + 1][lc] + cp[w0 + 2][lc] + cp[w0 + 3][lc];
        float q = cq[w0][lc] + cq[w0 + 1][lc] + cq[w0 + 2][lc] + cq[w0 + 3][lc];
        int rep = (blockIdx.x & (NREP - 1)) * 128 + t;
        atomicAdd(&csr[rep], s);
        atomicAdd(&cqr[rep], q);
    }
}

// BN + relu + residual; folds the NREP stat replicas in LDS (no k_red).
// 16 elems/thread, 4096 elems (32 rows) per block.
__global__ __launch_bounds__(256) void k_final(const uint* __restrict__ hb,
                                               const uint* __restrict__ xb,
                                               const float* __restrict__ gamma,
                                               const float* __restrict__ beta,
                                               const float* __restrict__ csr,
                                               const float* __restrict__ cqr,
                                               float* __restrict__ out, int out_size) {
    __shared__ float sa[128], sb[128];
    int t = threadIdx.x;
    const float invN = 1.0f / NN;
    if (t < 128) {
        float s = 0.f;
        for (int i = 0; i < NREP; ++i) s += csr[i * 128 + t];
        sa[t] = s * invN;                       // mean (temp)
    } else {
        int c = t - 128;
        float s = 0.f;
        for (int i = 0; i < NREP; ++i) s += cqr[i * 128 + c];
        sb[c] = s * invN;                       // E[h^2] (temp)
    }
    __syncthreads();
    if (t < 128) {
        float m = sa[t];
        float var = sb[t] - m * m;
        float inv = rsqrtf(var + BN_EPS);
        float A = inv * gamma[t];
        float B = beta[t] - m * A;
        sa[t] = A; sb[t] = B;                   // res = max(h*A+B,0)+x
    }
    __syncthreads();

    int c0 = (t & 7) * 16;
    int u8 = blockIdx.x * 512 + t * 2;          // uint4 index (8 bf16 each)
    uint4 hv0 = ((const uint4*)hb)[u8], hv1 = ((const uint4*)hb)[u8 + 1];
    uint4 xv0 = ((const uint4*)xb)[u8], xv1 = ((const uint4*)xb)[u8 + 1];
    uint hu[8] = {hv0.x, hv0.y, hv0.z, hv0.w, hv1.x, hv1.y, hv1.z, hv1.w};
    uint xu[8] = {xv0.x, xv0.y, xv0.z, xv0.w, xv1.x, xv1.y, xv1.z, xv1.w};
    float res[16];
#pragma unroll
    for (int p = 0; p < 8; ++p) {
        int c = c0 + p * 2;
        float h0 = b2f(hu[p] & 0xFFFFu), h1 = b2f(hu[p] >> 16);
        float x0 = b2f(xu[p] & 0xFFFFu), x1 = b2f(xu[p] >> 16);
        res[2 * p]     = fmaxf(fmaf(h0, sa[c],     sb[c]),     0.f) + x0;
        res[2 * p + 1] = fmaxf(fmaf(h1, sa[c + 1], sb[c + 1]), 0.f) + x1;
    }
    float4* o4 = (float4*)out;
    int ob = blockIdx.x * 1024 + t * 4;
#pragma unroll
    for (int q = 0; q < 4; ++q)
        o4[ob + q] = (float4){res[4 * q], res[4 * q + 1], res[4 * q + 2], res[4 * q + 3]};
    if (blockIdx.x == 0 && t == 0 && out_size > ND) out[ND] = 0.0f;
}

extern "C" void kernel_launch(void* const* d_in, const int* in_sizes, int n_in,
                              void* d_out, int out_size, void* d_ws, size_t ws_size,
                              hipStream_t stream) {
    const float* x     = (const float*)d_in[0];
    const int*   ei    = (const int*)d_in[1];
    const float* W     = (const float*)d_in[2];
    const float* gamma = (const float*)d_in[4];
    const float* beta  = (const float*)d_in[5];
    float* ws = (float*)d_ws;
    float* out = (float*)d_out;

    uint*   hb       = (uint*)ws;
    uint*   xb       = hb + ND / 2;
    float*  csr      = (float*)(xb + ND / 2);          // 16*128
    float*  cqr      = csr + NREP * 128;               // 16*128
    int*    bktot    = (int*)(cqr + NREP * 128);       // 128 (zeroed)
    int*    bcur     = bktot + 128;                    // 128 (zeroed)
    int*    cnt      = bcur + 128;                     // NN
    int*    ptr0     = cnt + NN;                       // NN
    float*  dinv     = (float*)(ptr0 + NN);            // NN
    int*    srow     = (int*)(dinv + NN);              // E

    int E = in_sizes[1] / 2;
    uint* wb = (uint*)(srow + E);

    // pairs alias the hb region (dead until k_gg writes it):
    // pairs needs 2*E slots (1.6M); hb region = 6.4M slots.
    uint2* pairs = (uint2*)hb;

    int nbc = (ND / 8 + (DD * DD) / 8 + 255) / 256;
    int nbin = (E + EPB - 1) / EPB;

    // zero stat replicas + bucket totals + bucket cursors (contiguous)
    hipMemsetAsync(csr, 0, (size_t)(2 * NREP * 128 + 256) * 4, stream);
    k_prep<<<nbin + nbc, 256, 0, stream>>>(ei, bktot, E, nbin, x, xb, W, wb);
    k_bin<<<nbin, 256, 0, stream>>>(ei, bktot, bcur, pairs, E);
    k_cnt<<<NBKT, 256, 0, stream>>>(pairs, bktot, ptr0, cnt, dinv, srow);
    k_gg<<<(NN + 63) / 64, 512, 0, stream>>>(xb, srow, ptr0, cnt, dinv,
                                             (const ushort*)wb, (ushort*)hb, csr, cqr);
    k_final<<<ND / 4096, 256, 0, stream>>>(hb, xb, gamma, beta, csr, cqr,
                                           out, out_size);
}